// Round 5
// baseline (221.178 us; speedup 1.0000x reference)
//
#include <hip/hip_runtime.h>
#include <stdint.h>

// SelfAttention1D: B=8, C=256, L=2048, D=32, fp32 in/out, bf16 MFMA compute.
// Two kernels: proj (QKV GEMM, W converted in-kernel) and attn (fused).
//
// ws layout (bytes):
//   Qh  @ 0x000000 : bf16 [B][L][32]   Q pre-scaled by (1/sqrt(D))*log2(e) (1 MB)
//   Kth @ 0x100000 : bf16 [B][L][32]   K^T, d-contiguous (1 MB)
//   Vh  @ 0x200000 : bf16 [B][256][L]  V, j-contiguous (8 MB)
// total 10 MB

#define BB 8
#define CC 256
#define LL 2048
#define DD 32

typedef unsigned short u16;
typedef __attribute__((ext_vector_type(8))) short short8;
typedef __attribute__((ext_vector_type(4))) float f32x4;

#define SCALE_LOG2E 0.2550348612f

static __device__ __forceinline__ uint32_t pack2bf16(float hi, float lo) {
    return (__float_as_uint(hi) & 0xFFFF0000u) | (__float_as_uint(lo) >> 16);
}

static __device__ __forceinline__ float fexp2(float v) {
#if __has_builtin(__builtin_amdgcn_exp2f)
    return __builtin_amdgcn_exp2f(v);
#else
    return exp2f(v);
#endif
}

static __device__ __forceinline__ float frcp(float v) {
#if __has_builtin(__builtin_amdgcn_rcpf)
    return __builtin_amdgcn_rcpf(v);
#else
    return 1.0f / v;
#endif
}

// ---------------- kernel 1: QKV projection (W converted in-kernel) ----------------
// grid 256 = 8 b x 32 l-tiles(64), 512 thr (8 waves).
// LDS: xls[64 l][264] bf16 x-tile (staged once, transposed, b64 writes);
//      Wls[320 m][40] bf16 W k-slice (staged per k-iter, shared by all waves).
// Waves: wm = w>>1 (80 m-rows, 5 m-tiles), wn = w&1 (32 l-cols, 2 n-tiles).
// All frag reads are 16B-contiguous ds_read_b128 at the 8-round LDS minimum.
__global__ __launch_bounds__(512, 2) void proj_kernel(
    const float* __restrict__ x,
    const float* __restrict__ Wq, const float* __restrict__ bq,
    const float* __restrict__ Wk, const float* __restrict__ bk,
    const float* __restrict__ Wv, const float* __restrict__ bv,
    u16* __restrict__ Qh, u16* __restrict__ Kth, u16* __restrict__ Vh)
{
    __shared__ u16 xls[64 * 264];        // 33.8 KB
    __shared__ u16 Wls[320 * 40];        // 25.6 KB
    const int blk = blockIdx.x;
    const int b = blk & 7;
    const int l0 = (blk >> 3) << 6;
    const int tid = threadIdx.x;
    const int w = tid >> 6;
    const int lane = tid & 63;
    const int ln = lane & 15;
    const int q = lane >> 4;
    const int wm = w >> 1;               // 0..3 -> 80 m-rows
    const int wn = w & 1;                // 0..1 -> 32 l-cols

    // ---- stage x[256 c][64 l] fp32 -> xls[64 l][264] bf16 (transposed) ----
    // thread task: 4 rows (r..r+3) x 4 l; coalesced float4 reads, b64 LDS writes.
#pragma unroll
    for (int i = 0; i < 2; ++i) {
        const int id = tid + i * 512;
        const int r = (id >> 4) << 2;            // 0..252 step 4
        const int l4 = (id & 15) << 2;
        union { float4 v; float f[4]; } vv[4];
#pragma unroll
        for (int k = 0; k < 4; ++k)
            vv[k].v = *(const float4*)(x + ((size_t)(b * CC + r + k)) * LL + l0 + l4);
#pragma unroll
        for (int k = 0; k < 4; ++k) {
            uint2 d;
            d.x = pack2bf16(vv[1].f[k], vv[0].f[k]);
            d.y = pack2bf16(vv[3].f[k], vv[2].f[k]);
            *(uint2*)(&xls[(l4 + k) * 264 + r]) = d;   // elements (l4+k, r..r+3)
        }
    }

    f32x4 acc[5][2];
#pragma unroll
    for (int a = 0; a < 5; ++a)
#pragma unroll
        for (int c = 0; c < 2; ++c) acc[a][c] = (f32x4){0.f, 0.f, 0.f, 0.f};

    for (int kk = 0; kk < 8; ++kk) {
        const int k0 = kk * 32;
        __syncthreads();                 // guards xls (iter 0) + Wls reuse
        // ---- stage W[320][k0..k0+31] fp32 -> Wls[320][40] bf16 ----
#pragma unroll
        for (int i = 0; i < 5; ++i) {
            const int id = tid + i * 512;
            const int r = id >> 3;               // 0..319
            const int c4 = (id & 7) << 2;        // 0..28
            const float* src = (r < 32) ? (Wq + (size_t)r * CC)
                             : (r < 64) ? (Wk + (size_t)(r - 32) * CC)
                                        : (Wv + (size_t)(r - 64) * CC);
            union { float4 v; float f[4]; } t;
            t.v = *(const float4*)(src + k0 + c4);
            uint2 d;
            d.x = pack2bf16(t.f[1], t.f[0]);
            d.y = pack2bf16(t.f[3], t.f[2]);
            *(uint2*)(&Wls[r * 40 + c4]) = d;
        }
        __syncthreads();

        short8 bf[2];
#pragma unroll
        for (int nt = 0; nt < 2; ++nt)
            bf[nt] = *(const short8*)(&xls[(wn * 32 + nt * 16 + ln) * 264 + k0 + q * 8]);
#pragma unroll
        for (int mt = 0; mt < 5; ++mt) {
            const short8 af = *(const short8*)(&Wls[(wm * 80 + mt * 16 + ln) * 40 + q * 8]);
            acc[mt][0] = __builtin_amdgcn_mfma_f32_16x16x32_bf16(af, bf[0], acc[mt][0], 0, 0, 0);
            acc[mt][1] = __builtin_amdgcn_mfma_f32_16x16x32_bf16(af, bf[1], acc[mt][1], 0, 0, 0);
        }
    }

    // ---- epilogue ----
#pragma unroll
    for (int mt = 0; mt < 5; ++mt) {
        const int rg = wm * 80 + mt * 16 + q * 4;     // global output row
#pragma unroll
        for (int nt = 0; nt < 2; ++nt) {
            const int l = l0 + wn * 32 + nt * 16 + ln;
            if (rg < 32) {               // Q rows, pre-scaled
                float v0 = (acc[mt][nt][0] + bq[rg + 0]) * SCALE_LOG2E;
                float v1 = (acc[mt][nt][1] + bq[rg + 1]) * SCALE_LOG2E;
                float v2 = (acc[mt][nt][2] + bq[rg + 2]) * SCALE_LOG2E;
                float v3 = (acc[mt][nt][3] + bq[rg + 3]) * SCALE_LOG2E;
                uint2 o; o.x = pack2bf16(v1, v0); o.y = pack2bf16(v3, v2);
                *(uint2*)(Qh + ((size_t)(b * LL) + l) * DD + rg) = o;
            } else if (rg < 64) {        // K rows
                const int rk = rg - 32;
                float v0 = acc[mt][nt][0] + bk[rk + 0];
                float v1 = acc[mt][nt][1] + bk[rk + 1];
                float v2 = acc[mt][nt][2] + bk[rk + 2];
                float v3 = acc[mt][nt][3] + bk[rk + 3];
                uint2 o; o.x = pack2bf16(v1, v0); o.y = pack2bf16(v3, v2);
                *(uint2*)(Kth + ((size_t)(b * LL) + l) * DD + rk) = o;
            } else {                     // V rows -> Vh[b][c][l]
                const int cv = rg - 64;
#pragma unroll
                for (int rr = 0; rr < 4; ++rr) {
                    const float v = acc[mt][nt][rr] + bv[cv + rr];
                    Vh[((size_t)(b * CC) + cv + rr) * LL + l] = (u16)(__float_as_uint(v) >> 16);
                }
            }
        }
    }
}

// ---------------- kernel 2: fused attention (barrier-free main loop) ----------------
// grid 256 = (b = blk&7 -> XCD L2 affinity) x (i-tile 64). 1024 thr (16 waves
// = 4 waves/SIMD): wc = w>>2 (c-slice 64), wj = w&3 (j-slice 32 per 128-j step).
// Each wave independently: S^T = K.Q^T -> exp2 -> P via wave-private LDS
// (no __syncthreads in loop) -> O^T += V.P^T over its exclusive 64-c slice.
// Registers trimmed to ~128/wave so all 16 waves co-reside. Epilogue: obuf
// reuses the pbuf LDS region (union); O reduced over wj in 4 barriered passes.
__global__ __launch_bounds__(1024, 4) void attn_kernel(
    const u16* __restrict__ Qh, const u16* __restrict__ Kth,
    const u16* __restrict__ Vh, const float* __restrict__ x,
    const float* __restrict__ gamma, float* __restrict__ out)
{
    __shared__ __align__(16) char smem[81920];   // pbuf 16x64x40 u16 (80 KB) / obuf 256x68 f32 (68 KB)
    __shared__ float lbuf[16 * 64];              // 4 KB
    u16* pbuf = (u16*)smem;
    float* obuf = (float*)smem;

    const int blk = blockIdx.x;
    const int b = blk & 7;
    const int i0 = (blk >> 3) << 6;
    const int tid = threadIdx.x;
    const int w = tid >> 6;              // 0..15
    const int wc = w >> 2;               // 0..3 -> 64 c-rows
    const int wj = w & 3;                // 0..3 -> 32-j slice
    const int lane = tid & 63;
    const int ln = lane & 15;
    const int q = lane >> 4;

    u16* pb = pbuf + w * (64 * 40);
    const u16* Qb = Qh + ((size_t)(b * LL) + i0) * DD;
    const u16* Kb = Kth + (size_t)(b * LL) * DD;
    const u16* Vb = Vh + ((size_t)(b * CC) + wc * 64) * LL;

    short8 qf[4];
#pragma unroll
    for (int it = 0; it < 4; ++it)
        qf[it] = *(const short8*)(Qb + (size_t)(it * 16 + ln) * DD + q * 8);

    const f32x4 zf = {0.f, 0.f, 0.f, 0.f};
    f32x4 oacc[4][4];                    // [ct][it]
#pragma unroll
    for (int a = 0; a < 4; ++a)
#pragma unroll
        for (int c = 0; c < 4; ++c) oacc[a][c] = zf;
    float lsum[4] = {0.f, 0.f, 0.f, 0.f};

    for (int n = 0; n < 16; ++n) {
        const int jb = n * 128 + wj * 32;

        // K loads first (needed first), V loads issued behind them (consumed
        // after S+exp+LDS ~400 cyc later -> L2 latency hidden).
        const short8 kf0 = *(const short8*)(Kb + (size_t)(jb + ln) * DD + q * 8);
        const short8 kf1 = *(const short8*)(Kb + (size_t)(jb + 16 + ln) * DD + q * 8);
        short8 vf[4];
#pragma unroll
        for (int ct = 0; ct < 4; ++ct)
            vf[ct] = *(const short8*)(Vb + (size_t)(ct * 16 + ln) * LL + jb + q * 8);

        // ---- S phase: S^T = K.Q^T (32 j x 64 i), exp2, P -> private LDS ----
#pragma unroll
        for (int jt = 0; jt < 2; ++jt) {
            const short8 kf = jt ? kf1 : kf0;
#pragma unroll
            for (int it = 0; it < 4; ++it) {
                const f32x4 st = __builtin_amdgcn_mfma_f32_16x16x32_bf16(kf, qf[it], zf, 0, 0, 0);
                const float e0 = fexp2(st[0]), e1 = fexp2(st[1]);
                const float e2 = fexp2(st[2]), e3 = fexp2(st[3]);
                lsum[it] += (e0 + e1) + (e2 + e3);
                uint2 d; d.x = pack2bf16(e1, e0); d.y = pack2bf16(e3, e2);
                *(uint2*)(&pb[(it * 16 + ln) * 40 + jt * 16 + q * 4]) = d;
            }
        }

        // ---- PV: O^T += V.P^T over exclusive 64-c slice ----
#pragma unroll
        for (int it = 0; it < 4; ++it) {
            const short8 pf = *(const short8*)(&pb[(it * 16 + ln) * 40 + q * 8]);
#pragma unroll
            for (int ct = 0; ct < 4; ++ct)
                oacc[ct][it] = __builtin_amdgcn_mfma_f32_16x16x32_bf16(vf[ct], pf, oacc[ct][it], 0, 0, 0);
        }
    }

    // ---- l: reduce over q within wave; publish per-wave partials ----
#pragma unroll
    for (int it = 0; it < 4; ++it) {
        float s = lsum[it];
        s += __shfl_xor(s, 16);
        s += __shfl_xor(s, 32);
        lsum[it] = s;
    }
    if (q == 0) {
#pragma unroll
        for (int it = 0; it < 4; ++it) lbuf[w * 64 + it * 16 + ln] = lsum[it];
    }
    __syncthreads();                     // all pbuf reads done -> obuf may reuse smem

    // ---- O reduction over wj (4 serialized passes; wc slices disjoint) ----
#pragma unroll
    for (int p = 0; p < 4; ++p) {
        if (wj == p) {
#pragma unroll
            for (int ct = 0; ct < 4; ++ct)
#pragma unroll
                for (int it = 0; it < 4; ++it) {
                    const int i = it * 16 + ln;
#pragma unroll
                    for (int r = 0; r < 4; ++r) {
                        const int c = wc * 64 + ct * 16 + q * 4 + r;
                        if (p == 0) obuf[c * 68 + i] = oacc[ct][it][r];
                        else        obuf[c * 68 + i] += oacc[ct][it][r];
                    }
                }
        }
        __syncthreads();
    }

    // ---- finalize: out = gamma * O/l + x (coalesced float4) ----
    // lbuf summed over 16 waves counts each j 4x (wc duplicates) -> li = 4/s.
    const float g = gamma[0];
    const int i4 = (tid & 15) * 4;
    float4 sv = {0.f, 0.f, 0.f, 0.f};
#pragma unroll
    for (int ww = 0; ww < 16; ++ww) {
        const float4 lv = *(const float4*)&lbuf[ww * 64 + i4];
        sv.x += lv.x; sv.y += lv.y; sv.z += lv.z; sv.w += lv.w;
    }
    float4 li;
    li.x = 4.0f * frcp(sv.x); li.y = 4.0f * frcp(sv.y);
    li.z = 4.0f * frcp(sv.z); li.w = 4.0f * frcp(sv.w);

#pragma unroll
    for (int cc = 0; cc < 4; ++cc) {
        const int c = cc * 64 + (tid >> 4);
        const float4 ov = *(const float4*)&obuf[c * 68 + i4];
        const size_t idx = ((size_t)(b * CC + c)) * LL + i0 + i4;
        const float4 xv = *(const float4*)(x + idx);
        float4 o;
        o.x = g * (ov.x * li.x) + xv.x;
        o.y = g * (ov.y * li.y) + xv.y;
        o.z = g * (ov.z * li.z) + xv.z;
        o.w = g * (ov.w * li.w) + xv.w;
        *(float4*)(out + idx) = o;
    }
}

// ---------------- launcher ----------------
extern "C" void kernel_launch(void* const* d_in, const int* in_sizes, int n_in,
                              void* d_out, int out_size, void* d_ws, size_t ws_size,
                              hipStream_t stream)
{
    const float* x     = (const float*)d_in[0];
    const float* Wq    = (const float*)d_in[1];
    const float* bq    = (const float*)d_in[2];
    const float* Wk    = (const float*)d_in[3];
    const float* bk    = (const float*)d_in[4];
    const float* Wv    = (const float*)d_in[5];
    const float* bv    = (const float*)d_in[6];
    const float* gamma = (const float*)d_in[7];
    float* out = (float*)d_out;

    uint8_t* ws = (uint8_t*)d_ws;
    u16* Qh  = (u16*)(ws + 0x000000);
    u16* Kth = (u16*)(ws + 0x100000);
    u16* Vh  = (u16*)(ws + 0x200000);

    proj_kernel<<<256, 512, 0, stream>>>(x, Wq, bq, Wk, bk, Wv, bv, Qh, Kth, Vh);
    attn_kernel<<<256, 1024, 0, stream>>>(Qh, Kth, Vh, x, gamma, out);
}

// Round 6
// 173.976 us; speedup vs baseline: 1.2713x; 1.2713x over previous
//
#include <hip/hip_runtime.h>
#include <stdint.h>

// SelfAttention1D: B=8, C=256, L=2048, D=32, fp32 in/out, bf16 MFMA compute.
//
// ws layout (bytes):
//   Qh  @ 0x000000 : bf16 [B][L][32]   Q pre-scaled by (1/sqrt(D))*log2(e) (1 MB)
//   Kth @ 0x100000 : bf16 [B][L][32]   K^T, d-contiguous (1 MB)
//   Vh  @ 0x200000 : bf16 [B][256][L]  V, j-contiguous (8 MB)
//   Wh  @ 0xA00000 : bf16 [320][256]   rows 0-31 Wq, 32-63 Wk, 64-319 Wv (160 KB)
// total ~10.4 MB

#define BB 8
#define CC 256
#define LL 2048
#define DD 32

typedef unsigned short u16;
typedef __attribute__((ext_vector_type(8))) short short8;
typedef __attribute__((ext_vector_type(4))) float f32x4;

#define SCALE_LOG2E 0.2550348612f

static __device__ __forceinline__ uint32_t pack2bf16(float hi, float lo) {
    return (__float_as_uint(hi) & 0xFFFF0000u) | (__float_as_uint(lo) >> 16);
}

static __device__ __forceinline__ float fexp2(float v) {
#if __has_builtin(__builtin_amdgcn_exp2f)
    return __builtin_amdgcn_exp2f(v);
#else
    return exp2f(v);
#endif
}

static __device__ __forceinline__ float frcp(float v) {
#if __has_builtin(__builtin_amdgcn_rcpf)
    return __builtin_amdgcn_rcpf(v);
#else
    return 1.0f / v;
#endif
}

// ---------------- kernel 1: W -> bf16 (one-time) ----------------
__global__ __launch_bounds__(256) void prep_w_kernel(
    const float* __restrict__ Wq, const float* __restrict__ Wk,
    const float* __restrict__ Wv, u16* __restrict__ Wh)
{
    int idx = blockIdx.x * 256 + threadIdx.x;     // 320 rows * 64 float4
    int r = idx >> 6;
    int c4 = (idx & 63) << 2;
    const float* src;
    if (r < 32)       src = Wq + (size_t)r * CC + c4;
    else if (r < 64)  src = Wk + (size_t)(r - 32) * CC + c4;
    else              src = Wv + (size_t)(r - 64) * CC + c4;
    float4 v = *(const float4*)src;
    uint2 o;
    o.x = pack2bf16(v.y, v.x);
    o.y = pack2bf16(v.w, v.z);
    *(uint2*)(Wh + (size_t)r * CC + c4) = o;
}

// ---------------- kernel 2: QKV projection ----------------
// grid 256 = 8 b x 32 l-tiles(64), 512 thr (8 waves).
// x staged ONCE to LDS transposed bf16 (single barrier); K-loop has NO
// barriers: B-frags = ds_read_b128 from xls, A-frags = 16B-contiguous global
// loads from Wh (L1-resident: 20 KB/kk/block, 2x reuse across wn).
__global__ __launch_bounds__(512, 2) void proj_kernel(
    const float* __restrict__ x, const u16* __restrict__ Wh,
    const float* __restrict__ bq, const float* __restrict__ bk,
    const float* __restrict__ bv,
    u16* __restrict__ Qh, u16* __restrict__ Kth, u16* __restrict__ Vh)
{
    __shared__ u16 xls[64 * 264];        // 33.8 KB
    const int blk = blockIdx.x;
    const int b = blk & 7;
    const int l0 = (blk >> 3) << 6;
    const int tid = threadIdx.x;
    const int w = tid >> 6;
    const int lane = tid & 63;
    const int ln = lane & 15;
    const int q = lane >> 4;
    const int wm = w >> 1;               // 0..3 -> 80 m-rows
    const int wn = w & 1;                // 0..1 -> 32 l-cols

    // ---- stage x[256 c][64 l] fp32 -> xls[64 l][264] bf16 (transposed) ----
#pragma unroll
    for (int i = 0; i < 2; ++i) {
        const int id = tid + i * 512;
        const int r = (id >> 4) << 2;            // 0..252 step 4
        const int l4 = (id & 15) << 2;
        union { float4 v; float f[4]; } vv[4];
#pragma unroll
        for (int k = 0; k < 4; ++k)
            vv[k].v = *(const float4*)(x + ((size_t)(b * CC + r + k)) * LL + l0 + l4);
#pragma unroll
        for (int k = 0; k < 4; ++k) {
            uint2 d;
            d.x = pack2bf16(vv[1].f[k], vv[0].f[k]);
            d.y = pack2bf16(vv[3].f[k], vv[2].f[k]);
            *(uint2*)(&xls[(l4 + k) * 264 + r]) = d;
        }
    }
    __syncthreads();

    f32x4 acc[5][2];
#pragma unroll
    for (int a = 0; a < 5; ++a)
#pragma unroll
        for (int c = 0; c < 2; ++c) acc[a][c] = (f32x4){0.f, 0.f, 0.f, 0.f};

#pragma unroll
    for (int kk = 0; kk < 8; ++kk) {
        const int k0 = kk * 32;
        short8 bf[2];
#pragma unroll
        for (int nt = 0; nt < 2; ++nt)
            bf[nt] = *(const short8*)(&xls[(wn * 32 + nt * 16 + ln) * 264 + k0 + q * 8]);
#pragma unroll
        for (int mt = 0; mt < 5; ++mt) {
            const short8 af = *(const short8*)(Wh + (size_t)(wm * 80 + mt * 16 + ln) * CC + k0 + q * 8);
            acc[mt][0] = __builtin_amdgcn_mfma_f32_16x16x32_bf16(af, bf[0], acc[mt][0], 0, 0, 0);
            acc[mt][1] = __builtin_amdgcn_mfma_f32_16x16x32_bf16(af, bf[1], acc[mt][1], 0, 0, 0);
        }
    }

    // ---- epilogue ----
#pragma unroll
    for (int mt = 0; mt < 5; ++mt) {
        const int rg = wm * 80 + mt * 16 + q * 4;     // global output row
#pragma unroll
        for (int nt = 0; nt < 2; ++nt) {
            const int l = l0 + wn * 32 + nt * 16 + ln;
            if (rg < 32) {               // Q rows, pre-scaled
                float v0 = (acc[mt][nt][0] + bq[rg + 0]) * SCALE_LOG2E;
                float v1 = (acc[mt][nt][1] + bq[rg + 1]) * SCALE_LOG2E;
                float v2 = (acc[mt][nt][2] + bq[rg + 2]) * SCALE_LOG2E;
                float v3 = (acc[mt][nt][3] + bq[rg + 3]) * SCALE_LOG2E;
                uint2 o; o.x = pack2bf16(v1, v0); o.y = pack2bf16(v3, v2);
                *(uint2*)(Qh + ((size_t)(b * LL) + l) * DD + rg) = o;
            } else if (rg < 64) {        // K rows
                const int rk = rg - 32;
                float v0 = acc[mt][nt][0] + bk[rk + 0];
                float v1 = acc[mt][nt][1] + bk[rk + 1];
                float v2 = acc[mt][nt][2] + bk[rk + 2];
                float v3 = acc[mt][nt][3] + bk[rk + 3];
                uint2 o; o.x = pack2bf16(v1, v0); o.y = pack2bf16(v3, v2);
                *(uint2*)(Kth + ((size_t)(b * LL) + l) * DD + rk) = o;
            } else {                     // V rows -> Vh[b][c][l]
                const int cv = rg - 64;
#pragma unroll
                for (int rr = 0; rr < 4; ++rr) {
                    const float v = acc[mt][nt][rr] + bv[cv + rr];
                    Vh[((size_t)(b * CC) + cv + rr) * LL + l] = (u16)(__float_as_uint(v) >> 16);
                }
            }
        }
    }
}

// ---------------- kernel 3: fused attention ----------------
// grid 512 = (b = blk&7 -> XCD L2 affinity) x (i-tile 32) -> 2 blocks/CU,
// 512 thr (8 waves) => 4 waves/SIMD TLP. launch_bounds(512,4) caps VGPR at
// 128; kernel uses ~118 (no spill). Waves fully independent in main loop:
// wc = w>>1 (c-slice 64), wj = w&1 (j-half 1024). Per 32-j iter: S^T = K.Q^T
// -> exp2 -> P via wave-private LDS (no barriers) -> O^T += V.P^T.
// Epilogue: obuf reuses pbuf LDS; O reduced over wj in 2 barriered passes.
__global__ __launch_bounds__(512, 4) void attn_kernel(
    const u16* __restrict__ Qh, const u16* __restrict__ Kth,
    const u16* __restrict__ Vh, const float* __restrict__ x,
    const float* __restrict__ gamma, float* __restrict__ out)
{
    __shared__ __align__(16) char smem[36864];   // pbuf 8x32x40 u16 (20 KB) / obuf 256x36 f32 (36 KB)
    __shared__ float lbuf[8 * 32];               // 1 KB
    u16* pbuf = (u16*)smem;
    float* obuf = (float*)smem;

    const int blk = blockIdx.x;
    const int b = blk & 7;
    const int i0 = (blk >> 3) << 5;      // i-tile 32
    const int tid = threadIdx.x;
    const int w = tid >> 6;              // 0..7
    const int wc = w >> 1;               // 0..3 -> 64 c-rows
    const int wj = w & 1;                // 0..1 -> j-half 1024
    const int lane = tid & 63;
    const int ln = lane & 15;
    const int q = lane >> 4;

    u16* pb = pbuf + w * (32 * 40);
    const u16* Qb = Qh + ((size_t)(b * LL) + i0) * DD;
    const u16* Kb = Kth + (size_t)(b * LL) * DD;
    const u16* Vb = Vh + ((size_t)(b * CC) + wc * 64) * LL;

    short8 qf[2];
#pragma unroll
    for (int it = 0; it < 2; ++it)
        qf[it] = *(const short8*)(Qb + (size_t)(it * 16 + ln) * DD + q * 8);

    const f32x4 zf = {0.f, 0.f, 0.f, 0.f};
    f32x4 oacc[4][2];                    // [ct][it] = 32 VGPRs
#pragma unroll
    for (int a = 0; a < 4; ++a)
#pragma unroll
        for (int c = 0; c < 2; ++c) oacc[a][c] = zf;
    float lsum[2] = {0.f, 0.f};

    for (int n = 0; n < 32; ++n) {
        const int jb = wj * 1024 + n * 32;

        // K first (needed first); V behind (consumed ~400 cyc later).
        const short8 kf0 = *(const short8*)(Kb + (size_t)(jb + ln) * DD + q * 8);
        const short8 kf1 = *(const short8*)(Kb + (size_t)(jb + 16 + ln) * DD + q * 8);
        short8 vf[4];
#pragma unroll
        for (int ct = 0; ct < 4; ++ct)
            vf[ct] = *(const short8*)(Vb + (size_t)(ct * 16 + ln) * LL + jb + q * 8);

        // ---- S phase: S^T = K.Q^T (32 j x 32 i), exp2, P -> private LDS ----
#pragma unroll
        for (int jt = 0; jt < 2; ++jt) {
            const short8 kf = jt ? kf1 : kf0;
#pragma unroll
            for (int it = 0; it < 2; ++it) {
                const f32x4 st = __builtin_amdgcn_mfma_f32_16x16x32_bf16(kf, qf[it], zf, 0, 0, 0);
                const float e0 = fexp2(st[0]), e1 = fexp2(st[1]);
                const float e2 = fexp2(st[2]), e3 = fexp2(st[3]);
                lsum[it] += (e0 + e1) + (e2 + e3);
                uint2 d; d.x = pack2bf16(e1, e0); d.y = pack2bf16(e3, e2);
                *(uint2*)(&pb[(it * 16 + ln) * 40 + jt * 16 + q * 4]) = d;
            }
        }

        // ---- PV: O^T += V.P^T over exclusive 64-c slice ----
#pragma unroll
        for (int it = 0; it < 2; ++it) {
            const short8 pf = *(const short8*)(&pb[(it * 16 + ln) * 40 + q * 8]);
#pragma unroll
            for (int ct = 0; ct < 4; ++ct)
                oacc[ct][it] = __builtin_amdgcn_mfma_f32_16x16x32_bf16(vf[ct], pf, oacc[ct][it], 0, 0, 0);
        }
    }

    // ---- l: reduce over q within wave; publish per-wave partials ----
#pragma unroll
    for (int it = 0; it < 2; ++it) {
        float s = lsum[it];
        s += __shfl_xor(s, 16);
        s += __shfl_xor(s, 32);
        lsum[it] = s;
    }
    if (q == 0) {
#pragma unroll
        for (int it = 0; it < 2; ++it) lbuf[w * 32 + it * 16 + ln] = lsum[it];
    }
    __syncthreads();                     // pbuf reads done -> obuf may reuse smem

    // ---- O reduction over wj (2 serialized passes; wc slices disjoint) ----
#pragma unroll
    for (int p = 0; p < 2; ++p) {
        if (wj == p) {
#pragma unroll
            for (int ct = 0; ct < 4; ++ct)
#pragma unroll
                for (int it = 0; it < 2; ++it) {
                    const int i = it * 16 + ln;
#pragma unroll
                    for (int r = 0; r < 4; ++r) {
                        const int c = wc * 64 + ct * 16 + q * 4 + r;
                        if (p == 0) obuf[c * 36 + i] = oacc[ct][it][r];
                        else        obuf[c * 36 + i] += oacc[ct][it][r];
                    }
                }
        }
        __syncthreads();
    }

    // ---- finalize: out = gamma * O/l + x (coalesced float4) ----
    // lbuf summed over 8 waves counts each j 4x (wc duplicates) -> li = 4/s.
    const float g = gamma[0];
    const int i4 = (tid & 7) * 4;
    float4 sv = {0.f, 0.f, 0.f, 0.f};
#pragma unroll
    for (int ww = 0; ww < 8; ++ww) {
        const float4 lv = *(const float4*)&lbuf[ww * 32 + i4];
        sv.x += lv.x; sv.y += lv.y; sv.z += lv.z; sv.w += lv.w;
    }
    float4 li;
    li.x = 4.0f * frcp(sv.x); li.y = 4.0f * frcp(sv.y);
    li.z = 4.0f * frcp(sv.z); li.w = 4.0f * frcp(sv.w);

#pragma unroll
    for (int cc = 0; cc < 4; ++cc) {
        const int c = cc * 64 + (tid >> 3);
        const float4 ov = *(const float4*)&obuf[c * 36 + i4];
        const size_t idx = ((size_t)(b * CC + c)) * LL + i0 + i4;
        const float4 xv = *(const float4*)(x + idx);
        float4 o;
        o.x = g * (ov.x * li.x) + xv.x;
        o.y = g * (ov.y * li.y) + xv.y;
        o.z = g * (ov.z * li.z) + xv.z;
        o.w = g * (ov.w * li.w) + xv.w;
        *(float4*)(out + idx) = o;
    }
}

// ---------------- launcher ----------------
extern "C" void kernel_launch(void* const* d_in, const int* in_sizes, int n_in,
                              void* d_out, int out_size, void* d_ws, size_t ws_size,
                              hipStream_t stream)
{
    const float* x     = (const float*)d_in[0];
    const float* Wq    = (const float*)d_in[1];
    const float* bq    = (const float*)d_in[2];
    const float* Wk    = (const float*)d_in[3];
    const float* bk    = (const float*)d_in[4];
    const float* Wv    = (const float*)d_in[5];
    const float* bv    = (const float*)d_in[6];
    const float* gamma = (const float*)d_in[7];
    float* out = (float*)d_out;

    uint8_t* ws = (uint8_t*)d_ws;
    u16* Qh  = (u16*)(ws + 0x000000);
    u16* Kth = (u16*)(ws + 0x100000);
    u16* Vh  = (u16*)(ws + 0x200000);
    u16* Wh  = (u16*)(ws + 0xA00000);

    prep_w_kernel<<<80, 256, 0, stream>>>(Wq, Wk, Wv, Wh);
    proj_kernel<<<256, 512, 0, stream>>>(x, Wh, bq, bk, bv, Qh, Kth, Vh);
    attn_kernel<<<512, 512, 0, stream>>>(Qh, Kth, Vh, x, gamma, out);
}

// Round 8
// 149.332 us; speedup vs baseline: 1.4811x; 1.1650x over previous
//
#include <hip/hip_runtime.h>
#include <stdint.h>

// SelfAttention1D: B=8, C=256, L=2048, D=32, fp32 in/out, bf16 MFMA compute.
// 3 plain kernels (cooperative launch crashes this harness - R7 post-mortem).
//
// ws layout (bytes):
//   Qh  @ 0x000000 : bf16 [B][L][32]   Q pre-scaled by (1/sqrt(D))*log2(e) (1 MB)
//   Kth @ 0x100000 : bf16 [B][L][32]   K^T, d-contiguous (1 MB)
//   Vh  @ 0x200000 : bf16 [B][256][L]  V, j-contiguous (8 MB)
//   Wh  @ 0xA00000 : bf16 [320][256]   rows 0-31 Wq, 32-63 Wk, 64-319 Wv (160 KB)

#define BB 8
#define CC 256
#define LL 2048
#define DD 32

typedef unsigned short u16;
typedef __attribute__((ext_vector_type(8))) short short8;
typedef __attribute__((ext_vector_type(4))) float f32x4;

#define SCALE_LOG2E 0.2550348612f

static __device__ __forceinline__ uint32_t pack2bf16(float hi, float lo) {
    return (__float_as_uint(hi) & 0xFFFF0000u) | (__float_as_uint(lo) >> 16);
}

static __device__ __forceinline__ float fexp2(float v) {
#if __has_builtin(__builtin_amdgcn_exp2f)
    return __builtin_amdgcn_exp2f(v);
#else
    return exp2f(v);
#endif
}

static __device__ __forceinline__ float frcp(float v) {
#if __has_builtin(__builtin_amdgcn_rcpf)
    return __builtin_amdgcn_rcpf(v);
#else
    return 1.0f / v;
#endif
}

// ---------------- kernel 1: W -> bf16 (one-time) ----------------
__global__ __launch_bounds__(256) void prep_w_kernel(
    const float* __restrict__ Wq, const float* __restrict__ Wk,
    const float* __restrict__ Wv, u16* __restrict__ Wh)
{
    int idx = blockIdx.x * 256 + threadIdx.x;     // 320 rows * 64 float4
    int r = idx >> 6;
    int c4 = (idx & 63) << 2;
    const float* src;
    if (r < 32)       src = Wq + (size_t)r * CC + c4;
    else if (r < 64)  src = Wk + (size_t)(r - 32) * CC + c4;
    else              src = Wv + (size_t)(r - 64) * CC + c4;
    float4 v = *(const float4*)src;
    uint2 o;
    o.x = pack2bf16(v.y, v.x);
    o.y = pack2bf16(v.w, v.z);
    *(uint2*)(Wh + (size_t)r * CC + c4) = o;
}

// ---------------- kernel 2: QKV projection ----------------
// grid 512 = 8 b x 64 l-tiles(32) -> 2 blocks/CU, 512 thr (8 waves)
// -> 4 waves/SIMD. Stage x[256 c][32 l] -> xls[32 l][264] bf16 transposed
// (one barrier); loop barrier-free: B-frags ds_read_b128 from xls, A-frags
// 16B-contiguous global from Wh (L1/L2-resident, shared across blocks).
__global__ __launch_bounds__(512, 4) void proj_kernel(
    const float* __restrict__ x, const u16* __restrict__ Wh,
    const float* __restrict__ bq, const float* __restrict__ bk,
    const float* __restrict__ bv,
    u16* __restrict__ Qh, u16* __restrict__ Kth, u16* __restrict__ Vh)
{
    __shared__ u16 xls[32 * 264];        // 16.9 KB
    const int blk = blockIdx.x;
    const int b = blk & 7;
    const int l0 = (blk >> 3) << 5;
    const int tid = threadIdx.x;
    const int w = tid >> 6;
    const int lane = tid & 63;
    const int ln = lane & 15;
    const int q = lane >> 4;
    const int wm = w >> 1;               // 0..3 -> 80 m-rows
    const int wn = w & 1;                // 0..1 -> 16 l-cols

    // ---- stage: task per thread: 4 c-rows x 4 l ----
    {
        const int r = (tid >> 3) << 2;           // 0..252 step 4
        const int l4 = (tid & 7) << 2;           // 0..28
        union { float4 v; float f[4]; } vv[4];
#pragma unroll
        for (int k = 0; k < 4; ++k)
            vv[k].v = *(const float4*)(x + ((size_t)(b * CC + r + k)) * LL + l0 + l4);
#pragma unroll
        for (int k = 0; k < 4; ++k) {
            uint2 d;
            d.x = pack2bf16(vv[1].f[k], vv[0].f[k]);
            d.y = pack2bf16(vv[3].f[k], vv[2].f[k]);
            *(uint2*)(&xls[(l4 + k) * 264 + r]) = d;
        }
    }
    __syncthreads();

    f32x4 acc[5];
#pragma unroll
    for (int a = 0; a < 5; ++a) acc[a] = (f32x4){0.f, 0.f, 0.f, 0.f};

#pragma unroll
    for (int kk = 0; kk < 8; ++kk) {
        const int k0 = kk * 32;
        const short8 bf = *(const short8*)(&xls[(wn * 16 + ln) * 264 + k0 + q * 8]);
#pragma unroll
        for (int mt = 0; mt < 5; ++mt) {
            const short8 af = *(const short8*)(Wh + (size_t)(wm * 80 + mt * 16 + ln) * CC + k0 + q * 8);
            acc[mt] = __builtin_amdgcn_mfma_f32_16x16x32_bf16(af, bf, acc[mt], 0, 0, 0);
        }
    }

    // ---- epilogue ----
    const int l = l0 + wn * 16 + ln;
#pragma unroll
    for (int mt = 0; mt < 5; ++mt) {
        const int rg = wm * 80 + mt * 16 + q * 4;     // global output row
        if (rg < 32) {               // Q rows, pre-scaled
            float v0 = (acc[mt][0] + bq[rg + 0]) * SCALE_LOG2E;
            float v1 = (acc[mt][1] + bq[rg + 1]) * SCALE_LOG2E;
            float v2 = (acc[mt][2] + bq[rg + 2]) * SCALE_LOG2E;
            float v3 = (acc[mt][3] + bq[rg + 3]) * SCALE_LOG2E;
            uint2 o; o.x = pack2bf16(v1, v0); o.y = pack2bf16(v3, v2);
            *(uint2*)(Qh + ((size_t)(b * LL) + l) * DD + rg) = o;
        } else if (rg < 64) {        // K rows
            const int rk = rg - 32;
            float v0 = acc[mt][0] + bk[rk + 0];
            float v1 = acc[mt][1] + bk[rk + 1];
            float v2 = acc[mt][2] + bk[rk + 2];
            float v3 = acc[mt][3] + bk[rk + 3];
            uint2 o; o.x = pack2bf16(v1, v0); o.y = pack2bf16(v3, v2);
            *(uint2*)(Kth + ((size_t)(b * LL) + l) * DD + rk) = o;
        } else {                     // V rows -> Vh[b][c][l]
            const int cv = rg - 64;
#pragma unroll
            for (int rr = 0; rr < 4; ++rr) {
                const float v = acc[mt][rr] + bv[cv + rr];
                Vh[((size_t)(b * CC) + cv + rr) * LL + l] = (u16)(__float_as_uint(v) >> 16);
            }
        }
    }
}

// ---------------- kernel 3: fused attention (software-pipelined) ----------------
// grid 256 = (b = blk&7 -> XCD L2 affinity) x (i-tile 64). 512 thr (8 waves):
// wc = w>>2 (c-half 128), wj = w&3 (j-slice 32 per 128-j step). Barrier-free
// main loop, DOUBLE-buffered wave-private P: iter n reads P(n) (written in
// iter n-1 -> LDS latency off critical path), computes S(n+1) from K frags
// prefetched TWO iters ahead (K latency off critical path), then PV(n).
// V issued at iter top, consumed at iter end (~500 cyc slack).
__global__ __launch_bounds__(512, 2) void attn_kernel(
    const u16* __restrict__ Qh, const u16* __restrict__ Kth,
    const u16* __restrict__ Vh, const float* __restrict__ x,
    const float* __restrict__ gamma, float* __restrict__ out)
{
    __shared__ __align__(16) char smem[81920];   // pbuf dbl 2x8x(64*40) u16 = 80 KB; obuf 256x68 f32 = 68 KB overlays
    __shared__ float lbuf[8 * 64];               // 2 KB
    u16* pbuf = (u16*)smem;
    float* obuf = (float*)smem;

    const int blk = blockIdx.x;
    const int b = blk & 7;
    const int i0 = (blk >> 3) << 6;
    const int tid = threadIdx.x;
    const int w = tid >> 6;              // 0..7
    const int wc = w >> 2;               // 0..1 -> 128 c-rows
    const int wj = w & 3;                // 0..3 -> 32-j slice per 128-j step
    const int lane = tid & 63;
    const int ln = lane & 15;
    const int q = lane >> 4;

    u16* pb0 = pbuf + w * (64 * 40);
    u16* pb1 = pbuf + (8 + w) * (64 * 40);
    const u16* Qb = Qh + ((size_t)(b * LL) + i0) * DD;
    const u16* Kb = Kth + (size_t)(b * LL) * DD;
    const u16* Vb = Vh + ((size_t)(b * CC) + wc * 128) * LL;

    short8 qf[4];
#pragma unroll
    for (int it = 0; it < 4; ++it)
        qf[it] = *(const short8*)(Qb + (size_t)(it * 16 + ln) * DD + q * 8);

    const f32x4 zf = {0.f, 0.f, 0.f, 0.f};
    f32x4 oacc[8][4];
#pragma unroll
    for (int a = 0; a < 8; ++a)
#pragma unroll
        for (int c = 0; c < 4; ++c) oacc[a][c] = zf;
    float lsum[4] = {0.f, 0.f, 0.f, 0.f};

    // ---- prologue: S(0) -> pb0; prefetch K(1) ----
    {
        const int jb = wj * 32;
        const short8 k0f = *(const short8*)(Kb + (size_t)(jb + ln) * DD + q * 8);
        const short8 k1f = *(const short8*)(Kb + (size_t)(jb + 16 + ln) * DD + q * 8);
#pragma unroll
        for (int jt = 0; jt < 2; ++jt) {
            const short8 kf = jt ? k1f : k0f;
#pragma unroll
            for (int it = 0; it < 4; ++it) {
                const f32x4 st = __builtin_amdgcn_mfma_f32_16x16x32_bf16(kf, qf[it], zf, 0, 0, 0);
                const float e0 = fexp2(st[0]), e1 = fexp2(st[1]);
                const float e2 = fexp2(st[2]), e3 = fexp2(st[3]);
                lsum[it] += (e0 + e1) + (e2 + e3);
                uint2 d; d.x = pack2bf16(e1, e0); d.y = pack2bf16(e3, e2);
                *(uint2*)(&pb0[(it * 16 + ln) * 40 + jt * 16 + q * 4]) = d;
            }
        }
    }
    // sk = K frags for S(n+1)
    short8 sk0 = *(const short8*)(Kb + (size_t)(128 + wj * 32 + ln) * DD + q * 8);
    short8 sk1 = *(const short8*)(Kb + (size_t)(128 + wj * 32 + 16 + ln) * DD + q * 8);

    for (int n = 0; n < 16; ++n) {
        u16* pbc = (n & 1) ? pb1 : pb0;
        u16* pbn = (n & 1) ? pb0 : pb1;
        const int jb = n * 128 + wj * 32;

        // P(n) read first (latency hidden behind S(n+1) compute)
        short8 pf[4];
#pragma unroll
        for (int it = 0; it < 4; ++it)
            pf[it] = *(const short8*)(&pbc[(it * 16 + ln) * 40 + q * 8]);

        // V(n) issued now, consumed at PV below (~500 cyc slack)
        short8 vf[8];
#pragma unroll
        for (int ct = 0; ct < 8; ++ct)
            vf[ct] = *(const short8*)(Vb + (size_t)(ct * 16 + ln) * LL + jb + q * 8);

        // K(n+2) prefetch (consumed next iter)
        const int jn2 = (n + 2 < 16) ? (n + 2) * 128 + wj * 32 : jb;
        const short8 nk0 = *(const short8*)(Kb + (size_t)(jn2 + ln) * DD + q * 8);
        const short8 nk1 = *(const short8*)(Kb + (size_t)(jn2 + 16 + ln) * DD + q * 8);

        // ---- S(n+1) from sk (in regs since last iter) -> pbn ----
        if (n < 15) {
#pragma unroll
            for (int jt = 0; jt < 2; ++jt) {
                const short8 kf = jt ? sk1 : sk0;
#pragma unroll
                for (int it = 0; it < 4; ++it) {
                    const f32x4 st = __builtin_amdgcn_mfma_f32_16x16x32_bf16(kf, qf[it], zf, 0, 0, 0);
                    const float e0 = fexp2(st[0]), e1 = fexp2(st[1]);
                    const float e2 = fexp2(st[2]), e3 = fexp2(st[3]);
                    lsum[it] += (e0 + e1) + (e2 + e3);
                    uint2 d; d.x = pack2bf16(e1, e0); d.y = pack2bf16(e3, e2);
                    *(uint2*)(&pbn[(it * 16 + ln) * 40 + jt * 16 + q * 4]) = d;
                }
            }
        }

        // ---- PV(n): O^T += V.P^T over exclusive 128-c half ----
#pragma unroll
        for (int ct = 0; ct < 8; ++ct)
#pragma unroll
            for (int it = 0; it < 4; ++it)
                oacc[ct][it] = __builtin_amdgcn_mfma_f32_16x16x32_bf16(vf[ct], pf[it], oacc[ct][it], 0, 0, 0);

        sk0 = nk0; sk1 = nk1;
    }

    // ---- l: reduce over q within wave; publish per-wave partials ----
#pragma unroll
    for (int it = 0; it < 4; ++it) {
        float s = lsum[it];
        s += __shfl_xor(s, 16);
        s += __shfl_xor(s, 32);
        lsum[it] = s;
    }
    if (q == 0) {
#pragma unroll
        for (int it = 0; it < 4; ++it) lbuf[w * 64 + it * 16 + ln] = lsum[it];
    }
    __syncthreads();                     // all pbuf reads done -> obuf may reuse smem

    // ---- O reduction over wj (4 serialized passes; wc halves disjoint) ----
#pragma unroll
    for (int p = 0; p < 4; ++p) {
        if (wj == p) {
#pragma unroll
            for (int ct = 0; ct < 8; ++ct)
#pragma unroll
                for (int it = 0; it < 4; ++it) {
                    const int i = it * 16 + ln;
#pragma unroll
                    for (int r = 0; r < 4; ++r) {
                        const int c = wc * 128 + ct * 16 + q * 4 + r;
                        if (p == 0) obuf[c * 68 + i] = oacc[ct][it][r];
                        else        obuf[c * 68 + i] += oacc[ct][it][r];
                    }
                }
        }
        __syncthreads();
    }

    // ---- finalize: out = gamma*O/l + x ; lbuf counts each j twice (2 wc) -> 2/s ----
    const float g = gamma[0];
    const int i4 = (tid & 15) * 4;
    float4 sv = {0.f, 0.f, 0.f, 0.f};
#pragma unroll
    for (int ww = 0; ww < 8; ++ww) {
        const float4 lv = *(const float4*)&lbuf[ww * 64 + i4];
        sv.x += lv.x; sv.y += lv.y; sv.z += lv.z; sv.w += lv.w;
    }
    float4 li;
    li.x = 2.0f * frcp(sv.x); li.y = 2.0f * frcp(sv.y);
    li.z = 2.0f * frcp(sv.z); li.w = 2.0f * frcp(sv.w);

#pragma unroll
    for (int cc = 0; cc < 8; ++cc) {
        const int c = cc * 32 + (tid >> 4);
        const float4 ov = *(const float4*)&obuf[c * 68 + i4];
        const size_t idx = ((size_t)(b * CC + c)) * LL + i0 + i4;
        const float4 xv = *(const float4*)(x + idx);
        float4 o;
        o.x = g * (ov.x * li.x) + xv.x;
        o.y = g * (ov.y * li.y) + xv.y;
        o.z = g * (ov.z * li.z) + xv.z;
        o.w = g * (ov.w * li.w) + xv.w;
        *(float4*)(out + idx) = o;
    }
}

// ---------------- launcher ----------------
extern "C" void kernel_launch(void* const* d_in, const int* in_sizes, int n_in,
                              void* d_out, int out_size, void* d_ws, size_t ws_size,
                              hipStream_t stream)
{
    const float* x     = (const float*)d_in[0];
    const float* Wq    = (const float*)d_in[1];
    const float* bq    = (const float*)d_in[2];
    const float* Wk    = (const float*)d_in[3];
    const float* bk    = (const float*)d_in[4];
    const float* Wv    = (const float*)d_in[5];
    const float* bv    = (const float*)d_in[6];
    const float* gamma = (const float*)d_in[7];
    float* out = (float*)d_out;

    uint8_t* ws = (uint8_t*)d_ws;
    u16* Qh  = (u16*)(ws + 0x000000);
    u16* Kth = (u16*)(ws + 0x100000);
    u16* Vh  = (u16*)(ws + 0x200000);
    u16* Wh  = (u16*)(ws + 0xA00000);

    prep_w_kernel<<<80, 256, 0, stream>>>(Wq, Wk, Wv, Wh);
    proj_kernel<<<512, 512, 0, stream>>>(x, Wh, bq, bk, bv, Qh, Kth, Vh);
    attn_kernel<<<256, 512, 0, stream>>>(Qh, Kth, Vh, x, gamma, out);
}